// Round 25
// baseline (143.965 us; speedup 1.0000x reference)
//
#include <hip/hip_runtime.h>
#include <hip/hip_fp16.h>
#include <math.h>

static constexpr int TPB = 256;
static constexpr int NPB_SHIFT = 7;   // 128 nodes per bucket
static constexpr int BCAP = 2816;     // arrival region per bucket; Poisson(2048) + 17 sigma
static constexpr int PCHUNK = 4096;   // edges per partition block (16/thread)
static constexpr int PF = 16;         // csr register-prefetch depth

// pk = (src << 15) | (fp16_bits(ew) & 0x7FFF)   [ew >= 0, sign bit 0]
__device__ __forceinline__ int p_src(unsigned p) { return (int)(p >> 15); }
__device__ __forceinline__ float p_w(unsigned p) {
  return __half2float(__ushort_as_half((unsigned short)(p & 0x7FFFu)));
}

struct h2x4 { __half2 a, b, c, d; };  // 16B row slice

// Each block bins PCHUNK edges into FIXED arrival regions [b*BCAP, b*BCAP+BCAP):
// LDS histogram -> one global atomic per touched bucket (private range) -> contiguous runs.
__global__ void k_partition(const int* __restrict__ src, const int* __restrict__ dst,
                            const float* __restrict__ ew, int* __restrict__ bkcnt,
                            unsigned* __restrict__ ppk, unsigned char* __restrict__ pld,
                            int E, int NB) {
  __shared__ int lh[1024];
  __shared__ int lbase[1024];
  __shared__ int lcur[1024];
  int tid = threadIdx.x;
  long long e0 = (long long)blockIdx.x * PCHUNK;
  int d[PCHUNK / TPB];
  unsigned pk[PCHUNK / TPB];
  for (int t = tid; t < NB; t += TPB) { lh[t] = 0; lcur[t] = 0; }
  __syncthreads();
#pragma unroll
  for (int r = 0; r < PCHUNK / TPB; ++r) {
    long long e = e0 + (long long)r * TPB + tid;
    if (e < E) {
      d[r] = dst[e];
      pk[r] = ((unsigned)src[e] << 15) |
              ((unsigned)__half_as_ushort(__float2half(ew[e])) & 0x7FFFu);
      atomicAdd(&lh[d[r] >> NPB_SHIFT], 1);
    } else {
      d[r] = -1;
    }
  }
  __syncthreads();
  for (int t = tid; t < NB; t += TPB)
    lbase[t] = lh[t] ? (t * BCAP + atomicAdd(&bkcnt[t], lh[t])) : 0;
  __syncthreads();
#pragma unroll
  for (int r = 0; r < PCHUNK / TPB; ++r) {
    if (d[r] >= 0) {
      int b = d[r] >> NPB_SHIFT;
      int pos = atomicAdd(&lcur[b], 1);
      size_t gp = (size_t)lbase[b] + pos;   // run stays inside region (17-sigma margin)
      ppk[gp] = pk[r];
      pld[gp] = (unsigned char)(d[r] & 127);
    }
  }
}

// One block per 128-node bucket: stage the bucket's ~2048 edges in LDS ONCE,
// count + scan -> CSR into csr sub-region, deg -> dis, fused GEMM1+scale (2 thr/node).
__global__ void __launch_bounds__(TPB) k_bucket(const unsigned* __restrict__ ppk,
                                                const unsigned char* __restrict__ pld,
                                                const int* __restrict__ bkcnt,
                                                unsigned* __restrict__ csr,
                                                int2* __restrict__ rc,
                                                float* __restrict__ dis,
                                                const float* __restrict__ x,
                                                const float* __restrict__ W1,
                                                __half2* __restrict__ hh, int n) {
  __shared__ unsigned lpk[BCAP];       // 11.3 KB
  __shared__ unsigned char lld[BCAP];  // 2.8 KB
  __shared__ float sW[45 * 32];        // 5.6 KB
  __shared__ int lcnt[128];
  __shared__ int lofs[128];
  __shared__ float lsum[128];
  int b = blockIdx.x;
  int t = threadIdx.x;
  int beg = b * BCAP;
  int m = bkcnt[b];
  if (m > BCAP) m = BCAP;  // statistically impossible
  if (t < 128) { lcnt[t] = 0; lsum[t] = 0.f; }
  for (int i = t; i < 45 * 32; i += TPB) sW[i] = W1[i];
  __syncthreads();
  for (int i = t; i < m; i += TPB) {
    unsigned pk = ppk[(size_t)beg + i];
    unsigned char ld = pld[(size_t)beg + i];
    lpk[i] = pk;
    lld[i] = ld;
    atomicAdd(&lcnt[ld], 1);
  }
  __syncthreads();
  int v = (t < 128) ? lcnt[t] : 0;
  if (t < 128) lofs[t] = v;
  __syncthreads();
  for (int off = 1; off < 128; off <<= 1) {  // inclusive scan over 128
    int tv = (t < 128 && t >= off) ? lofs[t - off] : 0;
    __syncthreads();
    if (t < 128) lofs[t] += tv;
    __syncthreads();
  }
  int gnode = (b << NPB_SHIFT) + t;
  if (t < 128) {
    int ex = lofs[t] - v;
    if (gnode < n) rc[gnode] = make_int2(beg + ex, v);
    lcnt[t] = ex;  // reuse as cursor
  }
  __syncthreads();
  for (int i = t; i < m; i += TPB) {
    unsigned pk = lpk[i];
    int ld = lld[i];
    int pos = atomicAdd(&lcnt[ld], 1);
    csr[(size_t)beg + pos] = pk;   // single-writer 11KB region: L2-resident
    atomicAdd(&lsum[ld], p_w(pk));
  }
  __syncthreads();
  int ln = t >> 1;        // local node 0..127
  int jh = t & 1;         // feature half
  int gnode2 = (b << NPB_SHIFT) + ln;
  if (gnode2 < n) {
    float dsc = rsqrtf(1.0f + lsum[ln]);
    if (jh == 0) dis[gnode2] = dsc;
    float xr[45];
#pragma unroll
    for (int k = 0; k < 45; ++k) xr[k] = x[(size_t)gnode2 * 45 + k];
    __half2* hw = hh + (size_t)gnode2 * 16 + jh * 8;
#pragma unroll
    for (int j2 = 0; j2 < 8; ++j2) {
      int j = jh * 16 + j2 * 2;
      float a0 = 0.f, a1 = 0.f;
#pragma unroll
      for (int k = 0; k < 45; ++k) {
        a0 = fmaf(xr[k], sW[k * 32 + j], a0);
        a1 = fmaf(xr[k], sW[k * 32 + j + 1], a1);
      }
      hw[j2] = __floats2half2_rn(a0 * dsc, a1 * dsc);
    }
  }
}

// Accumulate macro: one edge (pk) into bank (cc0..cc3).
#define ACC_EDGE(pk, cc0, cc1, cc2, cc3)                                             \
  {                                                                                  \
    h2x4 v = *reinterpret_cast<const h2x4*>(tbl + (size_t)p_src(pk) * 16);           \
    float w = p_w(pk);                                                               \
    float2 f;                                                                        \
    f = __half22float2(v.a); cc0.x = fmaf(w, f.x, cc0.x); cc0.y = fmaf(w, f.y, cc0.y); \
    f = __half22float2(v.b); cc1.x = fmaf(w, f.x, cc1.x); cc1.y = fmaf(w, f.y, cc1.y); \
    f = __half22float2(v.c); cc2.x = fmaf(w, f.x, cc2.x); cc2.y = fmaf(w, f.y, cc2.y); \
    f = __half22float2(v.d); cc3.x = fmaf(w, f.x, cc3.x); cc3.y = fmaf(w, f.y, cc3.y); \
  }

// Gather core: prefetch first PF csr entries to regs (independent loads), issue up to
// PF independent table loads (predicated, unrolled, alternating banks), rest unroll-4.
#define GATHER_CORE()                                                                \
  float2 c0 = {0.f, 0.f}, c1 = {0.f, 0.f}, c2 = {0.f, 0.f}, c3 = {0.f, 0.f};        \
  float2 d0 = {0.f, 0.f}, d1 = {0.f, 0.f}, d2 = {0.f, 0.f}, d3 = {0.f, 0.f};        \
  unsigned pr[PF];                                                                   \
  _Pragma("unroll") for (int i = 0; i < PF; ++i) { if (i < m) pr[i] = row[i]; }      \
  _Pragma("unroll") for (int i = 0; i < PF; ++i) {                                   \
    if (i < m) {                                                                     \
      if (i & 1) { ACC_EDGE(pr[i], d0, d1, d2, d3) }                                 \
      else       { ACC_EDGE(pr[i], c0, c1, c2, c3) }                                 \
    }                                                                                \
  }                                                                                  \
  int e = PF;                                                                        \
  for (; e + 3 < m; e += 4) {                                                        \
    unsigned p0 = row[e], p1 = row[e + 1], p2 = row[e + 2], p3 = row[e + 3];         \
    ACC_EDGE(p0, c0, c1, c2, c3)                                                     \
    ACC_EDGE(p1, d0, d1, d2, d3)                                                     \
    ACC_EDGE(p2, c0, c1, c2, c3)                                                     \
    ACC_EDGE(p3, d0, d1, d2, d3)                                                     \
  }                                                                                  \
  for (; e < m; ++e) { unsigned p = row[e]; ACC_EDGE(p, c0, c1, c2, c3) }            \
  c0.x += d0.x; c0.y += d0.y; c1.x += d1.x; c1.y += d1.y;                            \
  c2.x += d2.x; c2.y += d2.y; c3.x += d3.x; c3.y += d3.y;

// Gather: 4 lanes/node, lane owns 16B slice. TANH selects layer-1 vs layer-2 epilogue.
template <bool TANH>
__global__ void k_gather(const unsigned* __restrict__ csr, const int2* __restrict__ rc,
                         const float* __restrict__ dis, const __half2* __restrict__ hh,
                         const float* __restrict__ b1, __half2* __restrict__ outv, int n) {
  int gid = blockIdx.x * blockDim.x + threadIdx.x;
  int node = gid >> 2;
  if (node >= n) return;
  int q = (threadIdx.x & 3) * 4;          // this lane's half2 base (8 features)
  int2 r = rc[node];
  const unsigned* row = csr + r.x;
  int m = r.y;
  const __half2* tbl = hh + q;
  GATHER_CORE()
  float dd = dis[node];
  h2x4 own = *reinterpret_cast<const h2x4*>(hh + (size_t)node * 16 + q);
  __half2* op = outv + (size_t)node * 16 + q;
  float2 o0 = __half22float2(own.a), o1 = __half22float2(own.b);
  float2 o2 = __half22float2(own.c), o3 = __half22float2(own.d);
  if (TANH) {
    const float4* bp = reinterpret_cast<const float4*>(b1 + q * 2);
    float4 ba = bp[0], bb = bp[1];
    op[0] = __floats2half2_rn(dd * tanhf(ba.x + dd * (c0.x + o0.x)),
                              dd * tanhf(ba.y + dd * (c0.y + o0.y)));
    op[1] = __floats2half2_rn(dd * tanhf(ba.z + dd * (c1.x + o1.x)),
                              dd * tanhf(ba.w + dd * (c1.y + o1.y)));
    op[2] = __floats2half2_rn(dd * tanhf(bb.x + dd * (c2.x + o2.x)),
                              dd * tanhf(bb.y + dd * (c2.y + o2.y)));
    op[3] = __floats2half2_rn(dd * tanhf(bb.z + dd * (c3.x + o3.x)),
                              dd * tanhf(bb.w + dd * (c3.y + o3.y)));
  } else {
    op[0] = __floats2half2_rn(dd * (c0.x + o0.x), dd * (c0.y + o0.y));
    op[1] = __floats2half2_rn(dd * (c1.x + o1.x), dd * (c1.y + o1.y));
    op[2] = __floats2half2_rn(dd * (c2.x + o2.x), dd * (c2.y + o2.y));
    op[3] = __floats2half2_rn(dd * (c3.x + o3.x), dd * (c3.y + o3.y));
  }
}

// GEMM2 with W2 in registers (launch_bounds(256,2) prevents the round-23 spill).
__global__ void __launch_bounds__(TPB, 2)
k_gemm2r(const __half2* __restrict__ y, const float* __restrict__ W2,
         const float* __restrict__ b2, float* __restrict__ out, int n) {
  int lane = threadIdx.x & 63;
  int wid = (blockIdx.x * blockDim.x + threadIdx.x) >> 6;   // global wave id
  int nw = (gridDim.x * blockDim.x) >> 6;
  int c0 = lane * 2;
  float wr0[32], wr1[32];
#pragma unroll
  for (int k = 0; k < 32; ++k) {
    float2 wv = *reinterpret_cast<const float2*>(W2 + k * 128 + c0);
    wr0[k] = wv.x; wr1[k] = wv.y;
  }
  float2 bb = *reinterpret_cast<const float2*>(b2 + c0);

#define GEMM_NODE(node, ox, oy)                                                      \
  {                                                                                  \
    const h2x4* yr = reinterpret_cast<const h2x4*>(y + (size_t)(node) * 16);         \
    h2x4 yv[4] = {yr[0], yr[1], yr[2], yr[3]};                                       \
    _Pragma("unroll") for (int g = 0; g < 4; ++g) {                                  \
      __half2 hs[4] = {yv[g].a, yv[g].b, yv[g].c, yv[g].d};                          \
      _Pragma("unroll") for (int i = 0; i < 4; ++i) {                                \
        float2 f = __half22float2(hs[i]);                                            \
        ox = fmaf(f.x, wr0[g * 8 + i * 2], ox);                                      \
        oy = fmaf(f.x, wr1[g * 8 + i * 2], oy);                                      \
        ox = fmaf(f.y, wr0[g * 8 + i * 2 + 1], ox);                                  \
        oy = fmaf(f.y, wr1[g * 8 + i * 2 + 1], oy);                                  \
      }                                                                              \
    }                                                                                \
  }

  int node = wid * 2;
  int stride = nw * 2;
  for (; node + 1 < n; node += stride) {
    float a0 = bb.x, a1 = bb.y, b0 = bb.x, b1v = bb.y;
    GEMM_NODE(node, a0, a1)
    GEMM_NODE(node + 1, b0, b1v)
    *reinterpret_cast<float2*>(out + (size_t)node * 128 + c0) = make_float2(a0, a1);
    *reinterpret_cast<float2*>(out + (size_t)(node + 1) * 128 + c0) = make_float2(b0, b1v);
  }
  if (node < n) {
    float a0 = bb.x, a1 = bb.y;
    GEMM_NODE(node, a0, a1)
    *reinterpret_cast<float2*>(out + (size_t)node * 128 + c0) = make_float2(a0, a1);
  }
#undef GEMM_NODE
}

static inline dim3 gx(long long work) { return dim3((unsigned)((work + TPB - 1) / TPB)); }

extern "C" void kernel_launch(void* const* d_in, const int* in_sizes, int n_in,
                              void* d_out, int out_size, void* d_ws, size_t ws_size,
                              hipStream_t stream) {
  const float* x   = (const float*)d_in[0];
  const int*   src = (const int*)d_in[1];
  const int*   dst = (const int*)d_in[2];
  const float* ew  = (const float*)d_in[3];
  const float* W1  = (const float*)d_in[4];
  const float* b1  = (const float*)d_in[5];
  const float* W2  = (const float*)d_in[6];
  const float* b2  = (const float*)d_in[7];
  float* out = (float*)d_out;

  const int n = in_sizes[0] / 45;  // 100000
  const int E = in_sizes[1];       // 1600000
  const int NB = (n + 127) >> NPB_SHIFT;  // 782 (<= 1024)

  char* w = (char*)d_ws;
  size_t o = 0;
  auto alloc = [&](size_t bytes) { void* p = w + o; o += ((bytes + 255) & ~(size_t)255); return p; };
  int*           bkcnt = (int*)          alloc((size_t)NB * 4);
  unsigned*      ppk   = (unsigned*)     alloc((size_t)NB * BCAP * 4);  // 8.8 MB arrival
  unsigned char* pld   = (unsigned char*)alloc((size_t)NB * BCAP);      // 2.2 MB arrival
  unsigned*      csr   = (unsigned*)     alloc((size_t)NB * BCAP * 4);  // 8.8 MB padded
  int2*          rc    = (int2*)         alloc((size_t)n * 8);
  float*         dis   = (float*)        alloc((size_t)n * 4);
  __half2*       hh    = (__half2*)      alloc((size_t)n * 32 * 2);     // 6.4 MB
  __half2*       ag1   = (__half2*)      alloc((size_t)n * 32 * 2);     // 6.4 MB
  __half2*       yb    = (__half2*)      alloc((size_t)n * 32 * 2);     // 3.2 MB used

  const int PB = (E + PCHUNK - 1) / PCHUNK;     // 391

  hipMemsetAsync(bkcnt, 0, (size_t)NB * 4, stream);
  k_partition<<<PB, TPB, 0, stream>>>(src, dst, ew, bkcnt, ppk, pld, E, NB);
  k_bucket<<<NB, TPB, 0, stream>>>(ppk, pld, bkcnt, csr, rc, dis, x, W1, hh, n);
  k_gather<true><<<gx((long long)n * 4), TPB, 0, stream>>>(csr, rc, dis, hh, b1, ag1, n);
  k_gather<false><<<gx((long long)n * 4), TPB, 0, stream>>>(csr, rc, dis, ag1, b1, yb, n);
  k_gemm2r<<<1024, TPB, 0, stream>>>(yb, W2, b2, out, n);
}

// Round 26
// 139.216 us; speedup vs baseline: 1.0341x; 1.0341x over previous
//
#include <hip/hip_runtime.h>
#include <hip/hip_fp16.h>
#include <math.h>

static constexpr int TPB = 256;
static constexpr int NPB_SHIFT = 8;   // 256 nodes per bucket (partition granularity)
static constexpr int BCAP = 5120;     // arrival region per bucket; Poisson(4096) + 16 sigma
static constexpr int HCAP = 2816;     // csr sub-region per half-bucket
static constexpr int CSTRIDE = 2 * HCAP;
static constexpr int PCHUNK = 4096;   // edges per partition block (16/thread)
static constexpr int PF = 16;         // csr register-prefetch depth

// pk = (src << 15) | (fp16_bits(ew) & 0x7FFF)   [ew >= 0, sign bit 0]
__device__ __forceinline__ int p_src(unsigned p) { return (int)(p >> 15); }
__device__ __forceinline__ float p_w(unsigned p) {
  return __half2float(__ushort_as_half((unsigned short)(p & 0x7FFFu)));
}

struct h2x4 { __half2 a, b, c, d; };  // 16B row slice

__device__ __forceinline__ __half2 shfl_h2(__half2 v, int mask) {
  int b = *reinterpret_cast<int*>(&v);
  int r = __shfl_xor(b, mask, 64);
  return *reinterpret_cast<__half2*>(&r);
}

// Each block bins PCHUNK edges into FIXED arrival regions [b*BCAP, b*BCAP+BCAP):
// LDS histogram -> one global atomic per touched bucket (private range) -> contiguous runs.
__global__ void k_partition(const int* __restrict__ src, const int* __restrict__ dst,
                            const float* __restrict__ ew, int* __restrict__ bkcnt,
                            unsigned* __restrict__ ppk, unsigned char* __restrict__ pld,
                            int E, int NB) {
  __shared__ int lh[512];
  __shared__ int lbase[512];
  __shared__ int lcur[512];
  int tid = threadIdx.x;
  long long e0 = (long long)blockIdx.x * PCHUNK;
  int d[PCHUNK / TPB];
  unsigned pk[PCHUNK / TPB];
  for (int t = tid; t < NB; t += TPB) { lh[t] = 0; lcur[t] = 0; }
  __syncthreads();
#pragma unroll
  for (int r = 0; r < PCHUNK / TPB; ++r) {
    long long e = e0 + (long long)r * TPB + tid;
    if (e < E) {
      d[r] = dst[e];
      pk[r] = ((unsigned)src[e] << 15) |
              ((unsigned)__half_as_ushort(__float2half(ew[e])) & 0x7FFFu);
      atomicAdd(&lh[d[r] >> NPB_SHIFT], 1);
    } else {
      d[r] = -1;
    }
  }
  __syncthreads();
  for (int t = tid; t < NB; t += TPB)
    lbase[t] = lh[t] ? (t * BCAP + atomicAdd(&bkcnt[t], lh[t])) : 0;
  __syncthreads();
#pragma unroll
  for (int r = 0; r < PCHUNK / TPB; ++r) {
    if (d[r] >= 0) {
      int b = d[r] >> NPB_SHIFT;
      int pos = atomicAdd(&lcur[b], 1);
      size_t gp = (size_t)lbase[b] + pos;   // run stays inside region (16-sigma margin)
      ppk[gp] = pk[r];
      pld[gp] = (unsigned char)(d[r] & 255);
    }
  }
}

// TWO blocks per bucket (half = 128 nodes each): each scans the bucket's arrival region
// (L2-hot), filters its half, builds CSR into its own fixed sub-region, computes dis,
// and does fused GEMM1+scale (2 threads/node). No LDS edge staging -> 7 KB LDS.
__global__ void __launch_bounds__(TPB) k_bucket(const unsigned* __restrict__ ppk,
                                                const unsigned char* __restrict__ pld,
                                                const int* __restrict__ bkcnt,
                                                unsigned* __restrict__ csr,
                                                int2* __restrict__ rc,
                                                float* __restrict__ dis,
                                                const float* __restrict__ x,
                                                const float* __restrict__ W1,
                                                __half2* __restrict__ hh, int n) {
  __shared__ float sW[45 * 32];        // 5.6 KB
  __shared__ int lcnt[128];
  __shared__ int lofs[128];
  __shared__ float lsum[128];
  int b = blockIdx.x >> 1;
  int half = blockIdx.x & 1;
  int t = threadIdx.x;
  int beg = b * BCAP;                       // arrival region
  int cbeg = b * CSTRIDE + half * HCAP;     // this half's csr sub-region
  int m = bkcnt[b];
  if (m > BCAP) m = BCAP;  // statistically impossible
  if (t < 128) { lcnt[t] = 0; lsum[t] = 0.f; }
  for (int i = t; i < 45 * 32; i += TPB) sW[i] = W1[i];
  __syncthreads();
  for (int i = t; i < m; i += TPB) {
    int ld = pld[(size_t)beg + i];
    if ((ld >> 7) == half) atomicAdd(&lcnt[ld & 127], 1);
  }
  __syncthreads();
  int v = (t < 128) ? lcnt[t] : 0;
  if (t < 128) lofs[t] = v;
  __syncthreads();
  for (int off = 1; off < 128; off <<= 1) {
    int tv = (t < 128 && t >= off) ? lofs[t - off] : 0;
    __syncthreads();
    if (t < 128) lofs[t] += tv;
    __syncthreads();
  }
  int gnode = (b << NPB_SHIFT) + half * 128 + t;
  if (t < 128) {
    int ex = lofs[t] - v;
    if (gnode < n) rc[gnode] = make_int2(cbeg + ex, v);
    lcnt[t] = ex;
  }
  __syncthreads();
  for (int i = t; i < m; i += TPB) {
    int ld = pld[(size_t)beg + i];
    if ((ld >> 7) == half) {
      unsigned pk = ppk[(size_t)beg + i];
      int pos = atomicAdd(&lcnt[ld & 127], 1);
      csr[(size_t)cbeg + pos] = pk;
      atomicAdd(&lsum[ld & 127], p_w(pk));
    }
  }
  __syncthreads();
  int ln = t >> 1;
  int jh = t & 1;
  int gnode2 = (b << NPB_SHIFT) + half * 128 + ln;
  if (gnode2 < n) {
    float dsc = rsqrtf(1.0f + lsum[ln]);
    if (jh == 0) dis[gnode2] = dsc;
    float xr[45];
#pragma unroll
    for (int k = 0; k < 45; ++k) xr[k] = x[(size_t)gnode2 * 45 + k];
    __half2* hw = hh + (size_t)gnode2 * 16 + jh * 8;
#pragma unroll
    for (int j2 = 0; j2 < 8; ++j2) {
      int j = jh * 16 + j2 * 2;
      float a0 = 0.f, a1 = 0.f;
#pragma unroll
      for (int k = 0; k < 45; ++k) {
        a0 = fmaf(xr[k], sW[k * 32 + j], a0);
        a1 = fmaf(xr[k], sW[k * 32 + j + 1], a1);
      }
      hw[j2] = __floats2half2_rn(a0 * dsc, a1 * dsc);
    }
  }
}

// Accumulate macro: one edge (pk) into bank (cc0..cc3).
#define ACC_EDGE(pk, cc0, cc1, cc2, cc3)                                             \
  {                                                                                  \
    h2x4 v = *reinterpret_cast<const h2x4*>(tbl + (size_t)p_src(pk) * 16);           \
    float w = p_w(pk);                                                               \
    float2 f;                                                                        \
    f = __half22float2(v.a); cc0.x = fmaf(w, f.x, cc0.x); cc0.y = fmaf(w, f.y, cc0.y); \
    f = __half22float2(v.b); cc1.x = fmaf(w, f.x, cc1.x); cc1.y = fmaf(w, f.y, cc1.y); \
    f = __half22float2(v.c); cc2.x = fmaf(w, f.x, cc2.x); cc2.y = fmaf(w, f.y, cc2.y); \
    f = __half22float2(v.d); cc3.x = fmaf(w, f.x, cc3.x); cc3.y = fmaf(w, f.y, cc3.y); \
  }

// Gather core: prefetch first PF csr entries to regs (independent loads), issue up to
// PF independent table loads (predicated, unrolled, alternating banks), rest unroll-4.
#define GATHER_CORE()                                                                \
  float2 c0 = {0.f, 0.f}, c1 = {0.f, 0.f}, c2 = {0.f, 0.f}, c3 = {0.f, 0.f};        \
  float2 d0 = {0.f, 0.f}, d1 = {0.f, 0.f}, d2 = {0.f, 0.f}, d3 = {0.f, 0.f};        \
  unsigned pr[PF];                                                                   \
  _Pragma("unroll") for (int i = 0; i < PF; ++i) { if (i < m) pr[i] = row[i]; }      \
  _Pragma("unroll") for (int i = 0; i < PF; ++i) {                                   \
    if (i < m) {                                                                     \
      if (i & 1) { ACC_EDGE(pr[i], d0, d1, d2, d3) }                                 \
      else       { ACC_EDGE(pr[i], c0, c1, c2, c3) }                                 \
    }                                                                                \
  }                                                                                  \
  int e = PF;                                                                        \
  for (; e + 3 < m; e += 4) {                                                        \
    unsigned p0 = row[e], p1 = row[e + 1], p2 = row[e + 2], p3 = row[e + 3];         \
    ACC_EDGE(p0, c0, c1, c2, c3)                                                     \
    ACC_EDGE(p1, d0, d1, d2, d3)                                                     \
    ACC_EDGE(p2, c0, c1, c2, c3)                                                     \
    ACC_EDGE(p3, d0, d1, d2, d3)                                                     \
  }                                                                                  \
  for (; e < m; ++e) { unsigned p = row[e]; ACC_EDGE(p, c0, c1, c2, c3) }            \
  c0.x += d0.x; c0.y += d0.y; c1.x += d1.x; c1.y += d1.y;                            \
  c2.x += d2.x; c2.y += d2.y; c3.x += d3.x; c3.y += d3.y;

// Layer-1 gather: 4 lanes/node, lane owns 16B slice. Epilogue: tanh+bias, fp16 out.
__global__ void k_gather1(const unsigned* __restrict__ csr, const int2* __restrict__ rc,
                          const float* __restrict__ dis, const __half2* __restrict__ hh,
                          const float* __restrict__ b1, __half2* __restrict__ outv, int n) {
  int gid = blockIdx.x * blockDim.x + threadIdx.x;
  int node = gid >> 2;
  if (node >= n) return;
  int q = (threadIdx.x & 3) * 4;          // this lane's half2 base (8 features)
  int2 r = rc[node];
  const unsigned* row = csr + r.x;
  int m = r.y;
  const __half2* tbl = hh + q;
  GATHER_CORE()
  float dd = dis[node];
  h2x4 own = *reinterpret_cast<const h2x4*>(hh + (size_t)node * 16 + q);
  __half2* op = outv + (size_t)node * 16 + q;
  float2 o0 = __half22float2(own.a), o1 = __half22float2(own.b);
  float2 o2 = __half22float2(own.c), o3 = __half22float2(own.d);
  const float4* bp = reinterpret_cast<const float4*>(b1 + q * 2);
  float4 ba = bp[0], bb = bp[1];
  op[0] = __floats2half2_rn(dd * tanhf(ba.x + dd * (c0.x + o0.x)),
                            dd * tanhf(ba.y + dd * (c0.y + o0.y)));
  op[1] = __floats2half2_rn(dd * tanhf(ba.z + dd * (c1.x + o1.x)),
                            dd * tanhf(ba.w + dd * (c1.y + o1.y)));
  op[2] = __floats2half2_rn(dd * tanhf(bb.x + dd * (c2.x + o2.x)),
                            dd * tanhf(bb.y + dd * (c2.y + o2.y)));
  op[3] = __floats2half2_rn(dd * tanhf(bb.z + dd * (c3.x + o3.x)),
                            dd * tanhf(bb.w + dd * (c3.y + o3.y)));
}

// Layer-2 gather FUSED with GEMM2: gather y (4 lanes/node, 8 vals each), shfl-share y
// within the 4-lane group (positional regs, runtime k-base), then out = y@W2 + b2.
__global__ void k_gather2g(const unsigned* __restrict__ csr, const int2* __restrict__ rc,
                           const float* __restrict__ dis, const __half2* __restrict__ hh,
                           const float* __restrict__ W2, const float* __restrict__ b2,
                           float* __restrict__ out, int n) {
  __shared__ float sW[32 * 128];  // 16 KB
  __shared__ float sB[128];
  for (int t = threadIdx.x; t < 32 * 128; t += blockDim.x) sW[t] = W2[t];
  if (threadIdx.x < 128) sB[threadIdx.x] = b2[threadIdx.x];
  __syncthreads();
  int gid = blockIdx.x * blockDim.x + threadIdx.x;
  int node = gid >> 2;
  if (node >= n) return;
  int lq = threadIdx.x & 3;               // lane's quarter
  int q = lq * 4;                         // half2 base
  int2 r = rc[node];
  const unsigned* row = csr + r.x;
  int m = r.y;
  const __half2* tbl = hh + q;
  GATHER_CORE()
  float dd = dis[node];
  h2x4 own = *reinterpret_cast<const h2x4*>(hh + (size_t)node * 16 + q);
  float2 o0 = __half22float2(own.a), o1 = __half22float2(own.b);
  float2 o2 = __half22float2(own.c), o3 = __half22float2(own.d);
  __half2 y0 = __floats2half2_rn(dd * (c0.x + o0.x), dd * (c0.y + o0.y));
  __half2 y1 = __floats2half2_rn(dd * (c1.x + o1.x), dd * (c1.y + o1.y));
  __half2 y2 = __floats2half2_rn(dd * (c2.x + o2.x), dd * (c2.y + o2.y));
  __half2 y3 = __floats2half2_rn(dd * (c3.x + o3.x), dd * (c3.y + o3.y));
  __half2 g1_0 = shfl_h2(y0, 1), g1_1 = shfl_h2(y1, 1), g1_2 = shfl_h2(y2, 1), g1_3 = shfl_h2(y3, 1);
  __half2 g2_0 = shfl_h2(y0, 2), g2_1 = shfl_h2(y1, 2), g2_2 = shfl_h2(y2, 2), g2_3 = shfl_h2(y3, 2);
  __half2 g3_0 = shfl_h2(y0, 3), g3_1 = shfl_h2(y1, 3), g3_2 = shfl_h2(y2, 3), g3_3 = shfl_h2(y3, 3);
  int g4 = lq * 4;  // output float4 base; chunks at j = g4 + qq*16 (conflict-free)
  float4 a[8];
#pragma unroll
  for (int qq = 0; qq < 8; ++qq) a[qq] = *reinterpret_cast<const float4*>(&sB[g4 + qq * 16]);
#define GEMM_GRP(kb, h0, h1, h2v, h3v)                                              \
  {                                                                                 \
    __half2 hv[4] = {h0, h1, h2v, h3v};                                             \
    _Pragma("unroll") for (int ii = 0; ii < 4; ++ii) {                              \
      float2 yv = __half22float2(hv[ii]);                                           \
      const float* w0 = &sW[((kb + ii) * 2) * 128 + g4];                            \
      const float* w1 = &sW[((kb + ii) * 2 + 1) * 128 + g4];                        \
      _Pragma("unroll") for (int qq = 0; qq < 8; ++qq) {                            \
        float4 wa = *reinterpret_cast<const float4*>(w0 + qq * 16);                 \
        float4 wb = *reinterpret_cast<const float4*>(w1 + qq * 16);                 \
        a[qq].x = fmaf(yv.x, wa.x, fmaf(yv.y, wb.x, a[qq].x));                      \
        a[qq].y = fmaf(yv.x, wa.y, fmaf(yv.y, wb.y, a[qq].y));                      \
        a[qq].z = fmaf(yv.x, wa.z, fmaf(yv.y, wb.z, a[qq].z));                      \
        a[qq].w = fmaf(yv.x, wa.w, fmaf(yv.y, wb.w, a[qq].w));                      \
      }                                                                             \
    }                                                                               \
  }
  GEMM_GRP(lq * 4, y0, y1, y2, y3)
  GEMM_GRP((lq ^ 1) * 4, g1_0, g1_1, g1_2, g1_3)
  GEMM_GRP((lq ^ 2) * 4, g2_0, g2_1, g2_2, g2_3)
  GEMM_GRP((lq ^ 3) * 4, g3_0, g3_1, g3_2, g3_3)
#undef GEMM_GRP
  float* op = out + (size_t)node * 128 + g4;
#pragma unroll
  for (int qq = 0; qq < 8; ++qq) *reinterpret_cast<float4*>(op + qq * 16) = a[qq];
}

static inline dim3 gx(long long work) { return dim3((unsigned)((work + TPB - 1) / TPB)); }

extern "C" void kernel_launch(void* const* d_in, const int* in_sizes, int n_in,
                              void* d_out, int out_size, void* d_ws, size_t ws_size,
                              hipStream_t stream) {
  const float* x   = (const float*)d_in[0];
  const int*   src = (const int*)d_in[1];
  const int*   dst = (const int*)d_in[2];
  const float* ew  = (const float*)d_in[3];
  const float* W1  = (const float*)d_in[4];
  const float* b1  = (const float*)d_in[5];
  const float* W2  = (const float*)d_in[6];
  const float* b2  = (const float*)d_in[7];
  float* out = (float*)d_out;

  const int n = in_sizes[0] / 45;  // 100000
  const int E = in_sizes[1];       // 1600000
  const int NB = (n + 255) >> NPB_SHIFT;  // 391 (<= 512)

  char* w = (char*)d_ws;
  size_t o = 0;
  auto alloc = [&](size_t bytes) { void* p = w + o; o += ((bytes + 255) & ~(size_t)255); return p; };
  int*           bkcnt = (int*)          alloc((size_t)NB * 4);
  unsigned*      ppk   = (unsigned*)     alloc((size_t)NB * BCAP * 4);     // 8 MB arrival
  unsigned char* pld   = (unsigned char*)alloc((size_t)NB * BCAP);         // 2 MB arrival
  unsigned*      csr   = (unsigned*)     alloc((size_t)NB * CSTRIDE * 4);  // 8.8 MB padded
  int2*          rc    = (int2*)         alloc((size_t)n * 8);
  float*         dis   = (float*)        alloc((size_t)n * 4);
  __half2*       hh    = (__half2*)      alloc((size_t)n * 32 * 2);        // 6.4 MB
  __half2*       ag1   = (__half2*)      alloc((size_t)n * 32 * 2);        // 6.4 MB

  const int PB = (E + PCHUNK - 1) / PCHUNK;     // 391

  hipMemsetAsync(bkcnt, 0, (size_t)NB * 4, stream);
  k_partition<<<PB, TPB, 0, stream>>>(src, dst, ew, bkcnt, ppk, pld, E, NB);
  k_bucket<<<NB * 2, TPB, 0, stream>>>(ppk, pld, bkcnt, csr, rc, dis, x, W1, hh, n);
  k_gather1<<<gx((long long)n * 4), TPB, 0, stream>>>(csr, rc, dis, hh, b1, ag1, n);
  k_gather2g<<<gx((long long)n * 4), TPB, 0, stream>>>(csr, rc, dis, ag1, W2, b2, out, n);
}